// Round 1
// baseline (724.066 us; speedup 1.0000x reference)
//
#include <hip/hip_runtime.h>

#define N_NODES 100000
#define N_EDGES 1000000
#define BN_EPS 1e-5f

// ---------------- ws layout ----------------
// A     : [N_NODES][128] f32 (51.2 MB). A[n][j] j<64 : W_in[j,:128]@x[n] + b_in[j]
//                                        j>=64: W_in[j-64,128:]@x[n]   (no bias)
// stats : 128 f32  (sum[64], sumsq[64])
// ss    : 128 f32  (scale[64], shift[64])
// flag  : 1 int    (1 -> edges are int64, 0 -> int32)

// Probe edge dtype on-device: if int64 (values < 2^31), every odd 32-bit word
// (high halves) of the first 32 entries is 0. 32 consecutive zero node-ids as
// int32 has probability ~0.
__global__ __launch_bounds__(64) void k_probe(const unsigned* __restrict__ eu,
                                              int* __restrict__ flag) {
  if (threadIdx.x == 0) {
    unsigned acc = 0;
#pragma unroll
    for (int i = 1; i < 64; i += 2) acc |= eu[i];
    *flag = (acc == 0) ? 1 : 0;
  }
}

// K1: per-node projection A[n][0..127]. Block = 256 threads: two 128-thread
// halves, each half handles a group of 4 nodes per iteration (j = t & 127).
// W' ([128 rows][128 k]) staged in LDS with float4-granule XOR swizzle
// (chunk' = chunk ^ (row&31)) -> conflict-free ds_read_b128.
// x rows read via wave-uniform addresses -> scalar loads (SGPR operands).
__global__ __launch_bounds__(256) void k1_precompute(
    const float* __restrict__ x, const float* __restrict__ W_in,
    const float* __restrict__ b_in, float* __restrict__ A,
    float* __restrict__ stats) {
  __shared__ float wl[128 * 128];
  const int t = threadIdx.x;
  if (blockIdx.x == 0 && t < 128) stats[t] = 0.f;  // stats consumed only by K2 (later in stream)
  // stage W' swizzled: row<64 -> W_in[row][k]; row>=64 -> W_in[row-64][128+k]
  for (int idx = t; idx < 128 * 32; idx += 256) {
    const int row = idx >> 5, c = idx & 31;
    const int cs = c ^ (row & 31);
    const float4 w4 = *(const float4*)(W_in + (row & 63) * 256 + ((row >> 6) << 7) + (c << 2));
    *(float4*)(&wl[row * 128 + (cs << 2)]) = w4;
  }
  __syncthreads();
  const int j = t & 127;
  const int half = t >> 7;
  const int jsw = j & 31;
  const float bj = (j < 64) ? b_in[j] : 0.f;
  for (int g = blockIdx.x; g < (N_NODES / 8); g += gridDim.x) {
    const int n0 = (g * 2 + half) * 4;
    const float* xp = x + (size_t)n0 * 128;
    float acc0 = bj, acc1 = bj, acc2 = bj, acc3 = bj;
#pragma unroll 4
    for (int k4 = 0; k4 < 32; ++k4) {
      const float4 w  = *(const float4*)(&wl[j * 128 + ((k4 ^ jsw) << 2)]);
      const float4 x0 = *(const float4*)(xp + (k4 << 2));
      const float4 x1 = *(const float4*)(xp + 128 + (k4 << 2));
      const float4 x2 = *(const float4*)(xp + 256 + (k4 << 2));
      const float4 x3 = *(const float4*)(xp + 384 + (k4 << 2));
      acc0 += w.x * x0.x; acc0 += w.y * x0.y; acc0 += w.z * x0.z; acc0 += w.w * x0.w;
      acc1 += w.x * x1.x; acc1 += w.y * x1.y; acc1 += w.z * x1.z; acc1 += w.w * x1.w;
      acc2 += w.x * x2.x; acc2 += w.y * x2.y; acc2 += w.z * x2.z; acc2 += w.w * x2.w;
      acc3 += w.x * x3.x; acc3 += w.y * x3.y; acc3 += w.z * x3.z; acc3 += w.w * x3.w;
    }
    A[(size_t)n0 * 128 + j]       = acc0;
    A[(size_t)(n0 + 1) * 128 + j] = acc1;
    A[(size_t)(n0 + 2) * 128 + j] = acc2;
    A[(size_t)(n0 + 3) * 128 + j] = acc3;
  }
}

// K2: BN statistics. Wave = 64 edges; h1 in registers; h2 channel-loop with
// scalar-loaded W_h rows; per-wave LDS transpose tile ([64e][65] pad) so lane c
// owns channel c; 2 atomics per wave at the end.
__global__ __launch_bounds__(128) void k2_stats(
    const float* __restrict__ A, const void* __restrict__ edges,
    const int* __restrict__ flag, const float* __restrict__ W_h,
    const float* __restrict__ b_h, float* __restrict__ stats) {
  __shared__ float tile[2][64 * 65];
  const int lane = threadIdx.x & 63;
  const int wid = threadIdx.x >> 6;
  float* tl = tile[wid];
  const int is64 = *flag;
  const long long* e64 = (const long long*)edges;
  const int* e32 = (const int*)edges;
  float vsum = 0.f, vsq = 0.f;
  const int wslot = blockIdx.x * 2 + wid;
  for (int chunk = wslot; chunk < N_EDGES / 64; chunk += gridDim.x * 2) {
    const int e = chunk * 64 + lane;
    int s, d;
    if (is64) { s = (int)e64[e]; d = (int)e64[N_EDGES + e]; }
    else      { s = e32[e];      d = e32[N_EDGES + e]; }
    const float* As = A + (size_t)s * 128;
    const float* Ad = A + (size_t)d * 128 + 64;
    float h1[64];
#pragma unroll
    for (int i = 0; i < 16; ++i) {
      const float4 a = *(const float4*)(As + (i << 2));
      const float4 b = *(const float4*)(Ad + (i << 2));
      h1[4 * i + 0] = fmaxf(a.x + b.x, 0.f);
      h1[4 * i + 1] = fmaxf(a.y + b.y, 0.f);
      h1[4 * i + 2] = fmaxf(a.z + b.z, 0.f);
      h1[4 * i + 3] = fmaxf(a.w + b.w, 0.f);
    }
#pragma unroll 2
    for (int c = 0; c < 64; ++c) {
      float acc = b_h[c];
      const float* wr = W_h + (c << 6);
#pragma unroll
      for (int k = 0; k < 64; ++k) acc += wr[k] * h1[k];
      tl[lane * 65 + c] = acc;  // transpose write, (lane+c)%32 -> conflict-free
    }
#pragma unroll 8
    for (int e2 = 0; e2 < 64; ++e2) {
      const float v = tl[e2 * 65 + lane];
      vsum += v;
      vsq += v * v;
    }
  }
  atomicAdd(&stats[lane], vsum);
  atomicAdd(&stats[64 + lane], vsq);
}

// K3: fold BN into per-channel scale/shift.
__global__ __launch_bounds__(64) void k3_finalize(
    const float* __restrict__ stats, const float* __restrict__ gamma,
    const float* __restrict__ beta, float* __restrict__ ss) {
  const int c = threadIdx.x;
  if (c < 64) {
    const float inv_e = 1.f / (float)N_EDGES;
    const float mean = stats[c] * inv_e;
    const float var = stats[64 + c] * inv_e - mean * mean;
    const float scale = gamma[c] * rsqrtf(var + BN_EPS);
    ss[c] = scale;
    ss[64 + c] = beta[c] - mean * scale;
  }
}

// K4: output pass. Recompute h1/h2 per edge, apply folded BN + ReLU + W_out dot.
__global__ __launch_bounds__(256) void k4_out(
    const float* __restrict__ A, const void* __restrict__ edges,
    const int* __restrict__ flag, const float* __restrict__ W_h,
    const float* __restrict__ b_h, const float* __restrict__ ss,
    const float* __restrict__ W_out, const float* __restrict__ b_out,
    float* __restrict__ out) {
  const int is64 = *flag;
  const long long* e64 = (const long long*)edges;
  const int* e32 = (const int*)edges;
  const float bo = b_out[0];
  for (int e = blockIdx.x * 256 + threadIdx.x; e < N_EDGES; e += gridDim.x * 256) {
    int s, d;
    if (is64) { s = (int)e64[e]; d = (int)e64[N_EDGES + e]; }
    else      { s = e32[e];      d = e32[N_EDGES + e]; }
    const float* As = A + (size_t)s * 128;
    const float* Ad = A + (size_t)d * 128 + 64;
    float h1[64];
#pragma unroll
    for (int i = 0; i < 16; ++i) {
      const float4 a = *(const float4*)(As + (i << 2));
      const float4 b = *(const float4*)(Ad + (i << 2));
      h1[4 * i + 0] = fmaxf(a.x + b.x, 0.f);
      h1[4 * i + 1] = fmaxf(a.y + b.y, 0.f);
      h1[4 * i + 2] = fmaxf(a.z + b.z, 0.f);
      h1[4 * i + 3] = fmaxf(a.w + b.w, 0.f);
    }
    float acc_out = bo;
#pragma unroll 2
    for (int c = 0; c < 64; ++c) {
      float acc = b_h[c];
      const float* wr = W_h + (c << 6);
#pragma unroll
      for (int k = 0; k < 64; ++k) acc += wr[k] * h1[k];
      const float y = fmaxf(fmaf(acc, ss[c], ss[64 + c]), 0.f);
      acc_out = fmaf(y, W_out[c], acc_out);
    }
    out[e] = acc_out;
  }
}

extern "C" void kernel_launch(void* const* d_in, const int* in_sizes, int n_in,
                              void* d_out, int out_size, void* d_ws, size_t ws_size,
                              hipStream_t stream) {
  const float* x     = (const float*)d_in[0];
  const void*  edges = d_in[1];
  const float* W_in  = (const float*)d_in[2];
  const float* b_in  = (const float*)d_in[3];
  const float* W_h   = (const float*)d_in[4];
  const float* b_h   = (const float*)d_in[5];
  const float* gamma = (const float*)d_in[6];
  const float* beta  = (const float*)d_in[7];
  const float* W_out = (const float*)d_in[8];
  const float* b_out = (const float*)d_in[9];
  float* out = (float*)d_out;

  char* base = (char*)d_ws;
  float* A     = (float*)base;
  float* stats = (float*)(base + (size_t)N_NODES * 128 * sizeof(float));
  float* ss    = stats + 128;
  int*   flag  = (int*)(ss + 128);

  k_probe<<<1, 64, 0, stream>>>((const unsigned*)edges, flag);
  k1_precompute<<<1024, 256, 0, stream>>>(x, W_in, b_in, A, stats);
  k2_stats<<<1024, 128, 0, stream>>>(A, edges, flag, W_h, b_h, stats);
  k3_finalize<<<1, 64, 0, stream>>>(stats, gamma, beta, ss);
  k4_out<<<2048, 256, 0, stream>>>(A, edges, flag, W_h, b_h, ss, W_out, b_out, out);
}

// Round 2
// 438.564 us; speedup vs baseline: 1.6510x; 1.6510x over previous
//
#include <hip/hip_runtime.h>

#define N_NODES 100000
#define N_EDGES 1000000
#define BN_EPS 1e-5f
#define N_CHUNKS (N_EDGES / 64)

typedef __attribute__((ext_vector_type(8))) short bf16x8;
typedef __attribute__((ext_vector_type(4))) float f32x4;

// ---------------- ws layout ----------------
// A     : [N_NODES][128] f32 (51.2 MB)
// stats : 128 f32  (S1[64]=sum g, S2[64]=sum g^2)   g = h1 @ W_h^T (no bias; b_h cancels in BN)
// ss    : 128 f32  (scale[64], shift[64])
// flag  : 1 int    (1 -> edges are int64, 0 -> int32)

__device__ __forceinline__ unsigned pk2(float a, float b) {  // 2x bf16 RNE pack
  unsigned ua = __builtin_bit_cast(unsigned, a);
  unsigned ub = __builtin_bit_cast(unsigned, b);
  ua += 0x7fffu + ((ua >> 16) & 1u);
  ub += 0x7fffu + ((ub >> 16) & 1u);
  return (ua >> 16) | (ub & 0xffff0000u);
}

__global__ __launch_bounds__(64) void k_probe(const unsigned* __restrict__ eu,
                                              int* __restrict__ flag) {
  if (threadIdx.x == 0) {
    unsigned acc = 0;
#pragma unroll
    for (int i = 1; i < 64; i += 2) acc |= eu[i];
    *flag = (acc == 0) ? 1 : 0;
  }
}

// K1: per-node projection A[n][0..127] (fp32 VALU GEMV, W' staged in LDS swizzled).
__global__ __launch_bounds__(256) void k1_precompute(
    const float* __restrict__ x, const float* __restrict__ W_in,
    const float* __restrict__ b_in, float* __restrict__ A,
    float* __restrict__ stats) {
  __shared__ float wl[128 * 128];
  const int t = threadIdx.x;
  if (blockIdx.x == 0 && t < 128) stats[t] = 0.f;
  for (int idx = t; idx < 128 * 32; idx += 256) {
    const int row = idx >> 5, c = idx & 31;
    const int cs = c ^ (row & 31);
    const float4 w4 = *(const float4*)(W_in + (row & 63) * 256 + ((row >> 6) << 7) + (c << 2));
    *(float4*)(&wl[row * 128 + (cs << 2)]) = w4;
  }
  __syncthreads();
  const int j = t & 127;
  const int half = t >> 7;
  const int jsw = j & 31;
  const float bj = (j < 64) ? b_in[j] : 0.f;
  for (int g = blockIdx.x; g < (N_NODES / 8); g += gridDim.x) {
    const int n0 = (g * 2 + half) * 4;
    const float* xp = x + (size_t)n0 * 128;
    float acc0 = bj, acc1 = bj, acc2 = bj, acc3 = bj;
#pragma unroll 4
    for (int k4 = 0; k4 < 32; ++k4) {
      const float4 w  = *(const float4*)(&wl[j * 128 + ((k4 ^ jsw) << 2)]);
      const float4 x0 = *(const float4*)(xp + (k4 << 2));
      const float4 x1 = *(const float4*)(xp + 128 + (k4 << 2));
      const float4 x2 = *(const float4*)(xp + 256 + (k4 << 2));
      const float4 x3 = *(const float4*)(xp + 384 + (k4 << 2));
      acc0 += w.x * x0.x; acc0 += w.y * x0.y; acc0 += w.z * x0.z; acc0 += w.w * x0.w;
      acc1 += w.x * x1.x; acc1 += w.y * x1.y; acc1 += w.z * x1.z; acc1 += w.w * x1.w;
      acc2 += w.x * x2.x; acc2 += w.y * x2.y; acc2 += w.z * x2.z; acc2 += w.w * x2.w;
      acc3 += w.x * x3.x; acc3 += w.y * x3.y; acc3 += w.z * x3.z; acc3 += w.w * x3.w;
    }
    A[(size_t)n0 * 128 + j]       = acc0;
    A[(size_t)(n0 + 1) * 128 + j] = acc1;
    A[(size_t)(n0 + 2) * 128 + j] = acc2;
    A[(size_t)(n0 + 3) * 128 + j] = acc3;
  }
}

// ---- shared MFMA helpers (k2/k4) ----
// LDS tiles [64 rows][64 bf16] as 8x 16B chunks/row, XOR swizzle chunk^=(row&7).
// A-frag (edges): row = 16*mt + (l&15), chunk = kk*4 + (l>>4), k = 8*(l>>4)+j.
// B-frag (channels from W_h[c][k]): row = 16*nt + (l&15), same chunk formula.
// C-frag: col(channel-within-tile) = l&15, row(edge) = 4*(l>>4) + reg.

__device__ __forceinline__ void stage_wh(const float* __restrict__ W_h, uint4* btile) {
  const int t = threadIdx.x;
#pragma unroll
  for (int rep = 0; rep < 2; ++rep) {
    const int idx = t + rep * 256;
    const int row = idx >> 3, c = idx & 7;
    const float* wp = W_h + row * 64 + c * 8;
    const float4 w0 = *(const float4*)wp;
    const float4 w1 = *(const float4*)(wp + 4);
    btile[row * 8 + (c ^ (row & 7))] =
        make_uint4(pk2(w0.x, w0.y), pk2(w0.z, w0.w), pk2(w1.x, w1.y), pk2(w1.z, w1.w));
  }
}

__device__ __forceinline__ void stage_h1(const float* __restrict__ As,
                                         const float* __restrict__ Ad,
                                         uint4* mytile, int lane) {
#pragma unroll
  for (int c = 0; c < 8; ++c) {
    const float4 a0 = *(const float4*)(As + c * 8);
    const float4 a1 = *(const float4*)(As + c * 8 + 4);
    const float4 d0 = *(const float4*)(Ad + c * 8);
    const float4 d1 = *(const float4*)(Ad + c * 8 + 4);
    const float h0 = fmaxf(a0.x + d0.x, 0.f), h1v = fmaxf(a0.y + d0.y, 0.f);
    const float h2 = fmaxf(a0.z + d0.z, 0.f), h3 = fmaxf(a0.w + d0.w, 0.f);
    const float h4 = fmaxf(a1.x + d1.x, 0.f), h5 = fmaxf(a1.y + d1.y, 0.f);
    const float h6 = fmaxf(a1.z + d1.z, 0.f), h7 = fmaxf(a1.w + d1.w, 0.f);
    mytile[lane * 8 + (c ^ (lane & 7))] =
        make_uint4(pk2(h0, h1v), pk2(h2, h3), pk2(h4, h5), pk2(h6, h7));
  }
}

// K2: BN statistics over g = h1 @ W_h^T via MFMA. Per-wave private 64-edge tiles.
__global__ __launch_bounds__(256) void k2_stats(
    const float* __restrict__ A, const void* __restrict__ edges,
    const int* __restrict__ flag, const float* __restrict__ W_h,
    float* __restrict__ stats) {
  __shared__ uint4 tiles[4][64 * 8];
  __shared__ uint4 btile[64 * 8];
  const int lane = threadIdx.x & 63;
  const int wid = threadIdx.x >> 6;
  const int l15 = lane & 15, l4 = lane >> 4, lsw = l15 & 7;
  uint4* mytile = tiles[wid];
  stage_wh(W_h, btile);
  __syncthreads();
  // preload all 8 B fragments (kept in VGPRs for the whole kernel)
  bf16x8 bfr[4][2];
#pragma unroll
  for (int nt = 0; nt < 4; ++nt)
#pragma unroll
    for (int kk = 0; kk < 2; ++kk)
      bfr[nt][kk] = __builtin_bit_cast(bf16x8,
          btile[(nt * 16 + l15) * 8 + ((kk * 4 + l4) ^ lsw)]);

  const int is64 = *flag;
  const long long* e64 = (const long long*)edges;
  const int* e32 = (const int*)edges;
  float vs[4] = {0.f, 0.f, 0.f, 0.f};
  float vq[4] = {0.f, 0.f, 0.f, 0.f};
  const int gwave = blockIdx.x * 4 + wid;
  const int nwaves = gridDim.x * 4;
  for (int chunk = gwave; chunk < N_CHUNKS; chunk += nwaves) {
    const int e = chunk * 64 + lane;
    int s, d;
    if (is64) { s = (int)e64[e]; d = (int)e64[N_EDGES + e]; }
    else      { s = e32[e];      d = e32[N_EDGES + e]; }
    stage_h1(A + (size_t)s * 128, A + (size_t)d * 128 + 64, mytile, lane);
    asm volatile("s_waitcnt lgkmcnt(0)" ::: "memory");
    __builtin_amdgcn_sched_barrier(0);
#pragma unroll
    for (int mt = 0; mt < 4; ++mt) {
      const int arow = (mt * 16 + l15) * 8;
      const bf16x8 a0 = __builtin_bit_cast(bf16x8, mytile[arow + ((l4) ^ lsw)]);
      const bf16x8 a1 = __builtin_bit_cast(bf16x8, mytile[arow + ((4 + l4) ^ lsw)]);
#pragma unroll
      for (int nt = 0; nt < 4; ++nt) {
        f32x4 cacc = {0.f, 0.f, 0.f, 0.f};
        cacc = __builtin_amdgcn_mfma_f32_16x16x32_bf16(a0, bfr[nt][0], cacc, 0, 0, 0);
        cacc = __builtin_amdgcn_mfma_f32_16x16x32_bf16(a1, bfr[nt][1], cacc, 0, 0, 0);
#pragma unroll
        for (int j = 0; j < 4; ++j) {
          vs[nt] += cacc[j];
          vq[nt] += cacc[j] * cacc[j];
        }
      }
    }
  }
#pragma unroll
  for (int nt = 0; nt < 4; ++nt) {
    float s1 = vs[nt], s2 = vq[nt];
    s1 += __shfl_xor(s1, 16, 64); s1 += __shfl_xor(s1, 32, 64);
    s2 += __shfl_xor(s2, 16, 64); s2 += __shfl_xor(s2, 32, 64);
    if (lane < 16) {
      atomicAdd(&stats[lane + 16 * nt], s1);
      atomicAdd(&stats[64 + lane + 16 * nt], s2);
    }
  }
}

// K3: fold BN into per-channel scale/shift (b_h cancels exactly).
__global__ __launch_bounds__(64) void k3_finalize(
    const float* __restrict__ stats, const float* __restrict__ gamma,
    const float* __restrict__ beta, float* __restrict__ ss) {
  const int c = threadIdx.x;
  if (c < 64) {
    const float inv_e = 1.f / (float)N_EDGES;
    const float mg = stats[c] * inv_e;
    const float var = stats[64 + c] * inv_e - mg * mg;
    const float scale = gamma[c] * rsqrtf(var + BN_EPS);
    ss[c] = scale;
    ss[64 + c] = beta[c] - scale * mg;
  }
}

// K4: output pass — recompute g via MFMA, y=relu(scale*g+shift), dot with W_out.
__global__ __launch_bounds__(256) void k4_out(
    const float* __restrict__ A, const void* __restrict__ edges,
    const int* __restrict__ flag, const float* __restrict__ W_h,
    const float* __restrict__ ss, const float* __restrict__ W_out,
    const float* __restrict__ b_out, float* __restrict__ out) {
  __shared__ uint4 tiles[4][64 * 8];
  __shared__ uint4 btile[64 * 8];
  const int lane = threadIdx.x & 63;
  const int wid = threadIdx.x >> 6;
  const int l15 = lane & 15, l4 = lane >> 4, lsw = l15 & 7;
  uint4* mytile = tiles[wid];
  stage_wh(W_h, btile);
  __syncthreads();
  bf16x8 bfr[4][2];
#pragma unroll
  for (int nt = 0; nt < 4; ++nt)
#pragma unroll
    for (int kk = 0; kk < 2; ++kk)
      bfr[nt][kk] = __builtin_bit_cast(bf16x8,
          btile[(nt * 16 + l15) * 8 + ((kk * 4 + l4) ^ lsw)]);
  float scl[4], shf[4], wo[4];
#pragma unroll
  for (int nt = 0; nt < 4; ++nt) {
    scl[nt] = ss[l15 + 16 * nt];
    shf[nt] = ss[64 + l15 + 16 * nt];
    wo[nt] = W_out[l15 + 16 * nt];
  }
  const float bo = b_out[0];
  const int is64 = *flag;
  const long long* e64 = (const long long*)edges;
  const int* e32 = (const int*)edges;
  const int gwave = blockIdx.x * 4 + wid;
  const int nwaves = gridDim.x * 4;
  for (int chunk = gwave; chunk < N_CHUNKS; chunk += nwaves) {
    const int e = chunk * 64 + lane;
    int s, d;
    if (is64) { s = (int)e64[e]; d = (int)e64[N_EDGES + e]; }
    else      { s = e32[e];      d = e32[N_EDGES + e]; }
    stage_h1(A + (size_t)s * 128, A + (size_t)d * 128 + 64, mytile, lane);
    asm volatile("s_waitcnt lgkmcnt(0)" ::: "memory");
    __builtin_amdgcn_sched_barrier(0);
#pragma unroll
    for (int mt = 0; mt < 4; ++mt) {
      const int arow = (mt * 16 + l15) * 8;
      const bf16x8 a0 = __builtin_bit_cast(bf16x8, mytile[arow + ((l4) ^ lsw)]);
      const bf16x8 a1 = __builtin_bit_cast(bf16x8, mytile[arow + ((4 + l4) ^ lsw)]);
      float t0 = 0.f, t1 = 0.f, t2 = 0.f, t3 = 0.f;
#pragma unroll
      for (int nt = 0; nt < 4; ++nt) {
        f32x4 cacc = {0.f, 0.f, 0.f, 0.f};
        cacc = __builtin_amdgcn_mfma_f32_16x16x32_bf16(a0, bfr[nt][0], cacc, 0, 0, 0);
        cacc = __builtin_amdgcn_mfma_f32_16x16x32_bf16(a1, bfr[nt][1], cacc, 0, 0, 0);
        t0 += fmaxf(fmaf(cacc[0], scl[nt], shf[nt]), 0.f) * wo[nt];
        t1 += fmaxf(fmaf(cacc[1], scl[nt], shf[nt]), 0.f) * wo[nt];
        t2 += fmaxf(fmaf(cacc[2], scl[nt], shf[nt]), 0.f) * wo[nt];
        t3 += fmaxf(fmaf(cacc[3], scl[nt], shf[nt]), 0.f) * wo[nt];
      }
      const int ebase = chunk * 64 + mt * 16 + 4 * l4;
#pragma unroll
      for (int j = 0; j < 4; ++j) {
        float r = (j == 0) ? t0 : (j == 1) ? t1 : (j == 2) ? t2 : t3;
        r += __shfl_xor(r, 1, 64);
        r += __shfl_xor(r, 2, 64);
        r += __shfl_xor(r, 4, 64);
        r += __shfl_xor(r, 8, 64);
        if (l15 == 0) out[ebase + j] = r + bo;
      }
    }
  }
}

extern "C" void kernel_launch(void* const* d_in, const int* in_sizes, int n_in,
                              void* d_out, int out_size, void* d_ws, size_t ws_size,
                              hipStream_t stream) {
  const float* x     = (const float*)d_in[0];
  const void*  edges = d_in[1];
  const float* W_in  = (const float*)d_in[2];
  const float* b_in  = (const float*)d_in[3];
  const float* W_h   = (const float*)d_in[4];
  const float* gamma = (const float*)d_in[6];
  const float* beta  = (const float*)d_in[7];
  const float* W_out = (const float*)d_in[8];
  const float* b_out = (const float*)d_in[9];
  float* out = (float*)d_out;

  char* base = (char*)d_ws;
  float* A     = (float*)base;
  float* stats = (float*)(base + (size_t)N_NODES * 128 * sizeof(float));
  float* ss    = stats + 128;
  int*   flag  = (int*)(ss + 128);

  k_probe<<<1, 64, 0, stream>>>((const unsigned*)edges, flag);
  k1_precompute<<<1024, 256, 0, stream>>>(x, W_in, b_in, A, stats);
  k2_stats<<<1024, 256, 0, stream>>>(A, edges, flag, W_h, stats);
  k3_finalize<<<1, 64, 0, stream>>>(stats, gamma, beta, ss);
  k4_out<<<1024, 256, 0, stream>>>(A, edges, flag, W_h, ss, W_out, b_out, out);
}

// Round 3
// 243.415 us; speedup vs baseline: 2.9746x; 1.8017x over previous
//
#include <hip/hip_runtime.h>
#include <hip/hip_bf16.h>

#define N_NODES 100000
#define N_EDGES 1000000
#define BN_EPS 1e-5f
#define N_CHUNKS (N_EDGES / 64)

typedef __attribute__((ext_vector_type(8))) short bf16x8;
typedef __attribute__((ext_vector_type(4))) float f32x4;

// ---------------- ws layout ----------------
// A     : [N_NODES][128] bf16 (25.6 MB). ch<64: W_in[ch,:128]@x[n]+b_in[ch]; ch>=64: W_in[ch-64,128:]@x[n]
// stats : 128 f32  (S1[64]=sum g, S2[64]=sum g^2),  g = h1 @ W_h^T (b_h cancels in BN)
// ss    : 128 f32  (scale[64], shift[64])
// flag  : 1 int    (1 -> edges int64, 0 -> int32)

__device__ __forceinline__ unsigned pk2(float a, float b) {  // 2x bf16 RNE pack
  unsigned ua = __builtin_bit_cast(unsigned, a);
  unsigned ub = __builtin_bit_cast(unsigned, b);
  ua += 0x7fffu + ((ua >> 16) & 1u);
  ub += 0x7fffu + ((ub >> 16) & 1u);
  return (ua >> 16) | (ub & 0xffff0000u);
}

__device__ __forceinline__ bf16x8 pack8(float4 v0, float4 v1) {
  uint4 u = make_uint4(pk2(v0.x, v0.y), pk2(v0.z, v0.w), pk2(v1.x, v1.y), pk2(v1.z, v1.w));
  return __builtin_bit_cast(bf16x8, u);
}

__global__ __launch_bounds__(64) void k_probe(const unsigned* __restrict__ eu,
                                              int* __restrict__ flag) {
  if (threadIdx.x == 0) {
    unsigned acc = 0;
#pragma unroll
    for (int i = 1; i < 64; i += 2) acc |= eu[i];
    *flag = (acc == 0) ? 1 : 0;
  }
}

// K1: A = x @ Wcat^T via swapped-operand MFMA (C^T = Wcat . x^T), no LDS.
// Block 256 = 4 waves; wave w: nodes nb+[(w>>1)*64, +64), channels cb=(w&1)*64 .. +64.
// W-frags (A-operand) in VGPRs; x rows loaded as B-operand frags; C rows = channels.
__global__ __launch_bounds__(256) void k1_mfma(
    const float* __restrict__ x, const float* __restrict__ W_in,
    const float* __restrict__ b_in, __hip_bfloat16* __restrict__ A,
    float* __restrict__ stats) {
  const int t = threadIdx.x;
  if (blockIdx.x == 0 && t < 128) stats[t] = 0.f;
  const int lane = t & 63;
  const int w = t >> 6;
  const int l15 = lane & 15, l4 = lane >> 4;
  const int nb = blockIdx.x * 128 + (w >> 1) * 64;
  const int cb = (w & 1) * 64;

  // Wcat fragments: lane holds Wcat[cb+16ct+l15][32kk+8l4 .. +8]
  bf16x8 wfrag[4][4];
#pragma unroll
  for (int ct = 0; ct < 4; ++ct) {
#pragma unroll
    for (int kk = 0; kk < 4; ++kk) {
      const float* wp = W_in + (16 * ct + l15) * 256 + (cb ? 128 : 0) + 32 * kk + 8 * l4;
      wfrag[ct][kk] = pack8(*(const float4*)wp, *(const float4*)(wp + 4));
    }
  }
  f32x4 acc[4][4];
#pragma unroll
  for (int nt = 0; nt < 4; ++nt)
#pragma unroll
    for (int ct = 0; ct < 4; ++ct)
      acc[nt][ct] = (f32x4){0.f, 0.f, 0.f, 0.f};

#pragma unroll
  for (int nt = 0; nt < 4; ++nt) {
    int node = nb + 16 * nt + l15;
    node = node < N_NODES ? node : N_NODES - 1;  // clamp loads; stores predicated
    const float* xr = x + (size_t)node * 128 + 8 * l4;
#pragma unroll
    for (int kk = 0; kk < 4; ++kk) {
      const bf16x8 xf = pack8(*(const float4*)(xr + 32 * kk), *(const float4*)(xr + 32 * kk + 4));
#pragma unroll
      for (int ct = 0; ct < 4; ++ct)
        acc[nt][ct] = __builtin_amdgcn_mfma_f32_16x16x32_bf16(wfrag[ct][kk], xf, acc[nt][ct], 0, 0, 0);
    }
  }

  // bias (only channels < 64, i.e. cb==0 waves), then pack + 8B stores
  float4 bv[4];
#pragma unroll
  for (int ct = 0; ct < 4; ++ct)
    bv[ct] = cb ? make_float4(0.f, 0.f, 0.f, 0.f) : *(const float4*)(b_in + 16 * ct + 4 * l4);
#pragma unroll
  for (int nt = 0; nt < 4; ++nt) {
    const int node = nb + 16 * nt + l15;
    if (node < N_NODES) {
      __hip_bfloat16* ap = A + (size_t)node * 128 + cb + 4 * l4;
#pragma unroll
      for (int ct = 0; ct < 4; ++ct) {
        uint2 u;
        u.x = pk2(acc[nt][ct][0] + bv[ct].x, acc[nt][ct][1] + bv[ct].y);
        u.y = pk2(acc[nt][ct][2] + bv[ct].z, acc[nt][ct][3] + bv[ct].w);
        *(uint2*)(ap + 16 * ct) = u;
      }
    }
  }
}

// ---- shared MFMA helpers (k2/k4) ----
// LDS tiles [64 rows][64 bf16] as 8x 16B chunks/row, XOR swizzle chunk^=(row&7).
// A-frag (edges): row = 16*mt + (l&15), chunk = kk*4 + (l>>4).
// B-frag (channels from W_h[c][k]): row = 16*nt + (l&15), same chunk formula.
// C-frag: col(channel) = l&15, row(edge) = 4*(l>>4) + reg.

__device__ __forceinline__ void stage_wh(const float* __restrict__ W_h, uint4* btile) {
  const int t = threadIdx.x;
#pragma unroll
  for (int rep = 0; rep < 2; ++rep) {
    const int idx = t + rep * 256;
    const int row = idx >> 3, c = idx & 7;
    const float* wp = W_h + row * 64 + c * 8;
    const float4 w0 = *(const float4*)wp;
    const float4 w1 = *(const float4*)(wp + 4);
    btile[row * 8 + (c ^ (row & 7))] =
        make_uint4(pk2(w0.x, w0.y), pk2(w0.z, w0.w), pk2(w1.x, w1.y), pk2(w1.z, w1.w));
  }
}

// h1 = relu(As + Ad) from bf16 A rows; packed unpack/add/relu/repack.
__device__ __forceinline__ void stage_h1(const __hip_bfloat16* __restrict__ As,
                                         const __hip_bfloat16* __restrict__ Ad,
                                         uint4* mytile, int lane) {
  const uint4* pa = (const uint4*)As;
  const uint4* pd = (const uint4*)Ad;
#pragma unroll
  for (int c = 0; c < 8; ++c) {
    const uint4 a = pa[c], d = pd[c];
    uint4 r;
    const unsigned* aw = (const unsigned*)&a;
    const unsigned* dw = (const unsigned*)&d;
    unsigned* rw = (unsigned*)&r;
#pragma unroll
    for (int q = 0; q < 4; ++q) {
      const float alo = __builtin_bit_cast(float, aw[q] << 16);
      const float ahi = __builtin_bit_cast(float, aw[q] & 0xffff0000u);
      const float dlo = __builtin_bit_cast(float, dw[q] << 16);
      const float dhi = __builtin_bit_cast(float, dw[q] & 0xffff0000u);
      rw[q] = pk2(fmaxf(alo + dlo, 0.f), fmaxf(ahi + dhi, 0.f));
    }
    mytile[lane * 8 + (c ^ (lane & 7))] = r;
  }
}

// K2: BN statistics over g = h1 @ W_h^T via MFMA. Per-wave private 64-edge tiles.
__global__ __launch_bounds__(256) void k2_stats(
    const __hip_bfloat16* __restrict__ A, const void* __restrict__ edges,
    const int* __restrict__ flag, const float* __restrict__ W_h,
    float* __restrict__ stats) {
  __shared__ uint4 tiles[4][64 * 8];
  __shared__ uint4 btile[64 * 8];
  const int lane = threadIdx.x & 63;
  const int wid = threadIdx.x >> 6;
  const int l15 = lane & 15, l4 = lane >> 4, lsw = l15 & 7;
  uint4* mytile = tiles[wid];
  stage_wh(W_h, btile);
  __syncthreads();
  bf16x8 bfr[4][2];
#pragma unroll
  for (int nt = 0; nt < 4; ++nt)
#pragma unroll
    for (int kk = 0; kk < 2; ++kk)
      bfr[nt][kk] = __builtin_bit_cast(bf16x8,
          btile[(nt * 16 + l15) * 8 + ((kk * 4 + l4) ^ lsw)]);

  const int is64 = *flag;
  const long long* e64 = (const long long*)edges;
  const int* e32 = (const int*)edges;
  float vs[4] = {0.f, 0.f, 0.f, 0.f};
  float vq[4] = {0.f, 0.f, 0.f, 0.f};
  const int gwave = blockIdx.x * 4 + wid;
  const int nwaves = gridDim.x * 4;
  for (int chunk = gwave; chunk < N_CHUNKS; chunk += nwaves) {
    const int e = chunk * 64 + lane;
    int s, d;
    if (is64) { s = (int)e64[e]; d = (int)e64[N_EDGES + e]; }
    else      { s = e32[e];      d = e32[N_EDGES + e]; }
    stage_h1(A + (size_t)s * 128, A + (size_t)d * 128 + 64, mytile, lane);
    asm volatile("s_waitcnt lgkmcnt(0)" ::: "memory");
    __builtin_amdgcn_sched_barrier(0);
#pragma unroll
    for (int mt = 0; mt < 4; ++mt) {
      const int arow = (mt * 16 + l15) * 8;
      const bf16x8 a0 = __builtin_bit_cast(bf16x8, mytile[arow + ((l4) ^ lsw)]);
      const bf16x8 a1 = __builtin_bit_cast(bf16x8, mytile[arow + ((4 + l4) ^ lsw)]);
#pragma unroll
      for (int nt = 0; nt < 4; ++nt) {
        f32x4 cacc = {0.f, 0.f, 0.f, 0.f};
        cacc = __builtin_amdgcn_mfma_f32_16x16x32_bf16(a0, bfr[nt][0], cacc, 0, 0, 0);
        cacc = __builtin_amdgcn_mfma_f32_16x16x32_bf16(a1, bfr[nt][1], cacc, 0, 0, 0);
#pragma unroll
        for (int j = 0; j < 4; ++j) {
          vs[nt] += cacc[j];
          vq[nt] += cacc[j] * cacc[j];
        }
      }
    }
  }
#pragma unroll
  for (int nt = 0; nt < 4; ++nt) {
    float s1 = vs[nt], s2 = vq[nt];
    s1 += __shfl_xor(s1, 16, 64); s1 += __shfl_xor(s1, 32, 64);
    s2 += __shfl_xor(s2, 16, 64); s2 += __shfl_xor(s2, 32, 64);
    if (lane < 16) {
      atomicAdd(&stats[lane + 16 * nt], s1);
      atomicAdd(&stats[64 + lane + 16 * nt], s2);
    }
  }
}

// K3: fold BN into per-channel scale/shift (b_h cancels exactly).
__global__ __launch_bounds__(64) void k3_finalize(
    const float* __restrict__ stats, const float* __restrict__ gamma,
    const float* __restrict__ beta, float* __restrict__ ss) {
  const int c = threadIdx.x;
  if (c < 64) {
    const float inv_e = 1.f / (float)N_EDGES;
    const float mg = stats[c] * inv_e;
    const float var = stats[64 + c] * inv_e - mg * mg;
    const float scale = gamma[c] * rsqrtf(var + BN_EPS);
    ss[c] = scale;
    ss[64 + c] = beta[c] - scale * mg;
  }
}

// K4: output pass — recompute g via MFMA, y=relu(scale*g+shift), dot with W_out.
__global__ __launch_bounds__(256) void k4_out(
    const __hip_bfloat16* __restrict__ A, const void* __restrict__ edges,
    const int* __restrict__ flag, const float* __restrict__ W_h,
    const float* __restrict__ ss, const float* __restrict__ W_out,
    const float* __restrict__ b_out, float* __restrict__ out) {
  __shared__ uint4 tiles[4][64 * 8];
  __shared__ uint4 btile[64 * 8];
  const int lane = threadIdx.x & 63;
  const int wid = threadIdx.x >> 6;
  const int l15 = lane & 15, l4 = lane >> 4, lsw = l15 & 7;
  uint4* mytile = tiles[wid];
  stage_wh(W_h, btile);
  __syncthreads();
  bf16x8 bfr[4][2];
#pragma unroll
  for (int nt = 0; nt < 4; ++nt)
#pragma unroll
    for (int kk = 0; kk < 2; ++kk)
      bfr[nt][kk] = __builtin_bit_cast(bf16x8,
          btile[(nt * 16 + l15) * 8 + ((kk * 4 + l4) ^ lsw)]);
  float scl[4], shf[4], wo[4];
#pragma unroll
  for (int nt = 0; nt < 4; ++nt) {
    scl[nt] = ss[l15 + 16 * nt];
    shf[nt] = ss[64 + l15 + 16 * nt];
    wo[nt] = W_out[l15 + 16 * nt];
  }
  const float bo = b_out[0];
  const int is64 = *flag;
  const long long* e64 = (const long long*)edges;
  const int* e32 = (const int*)edges;
  const int gwave = blockIdx.x * 4 + wid;
  const int nwaves = gridDim.x * 4;
  for (int chunk = gwave; chunk < N_CHUNKS; chunk += nwaves) {
    const int e = chunk * 64 + lane;
    int s, d;
    if (is64) { s = (int)e64[e]; d = (int)e64[N_EDGES + e]; }
    else      { s = e32[e];      d = e32[N_EDGES + e]; }
    stage_h1(A + (size_t)s * 128, A + (size_t)d * 128 + 64, mytile, lane);
    asm volatile("s_waitcnt lgkmcnt(0)" ::: "memory");
    __builtin_amdgcn_sched_barrier(0);
#pragma unroll
    for (int mt = 0; mt < 4; ++mt) {
      const int arow = (mt * 16 + l15) * 8;
      const bf16x8 a0 = __builtin_bit_cast(bf16x8, mytile[arow + ((l4) ^ lsw)]);
      const bf16x8 a1 = __builtin_bit_cast(bf16x8, mytile[arow + ((4 + l4) ^ lsw)]);
      float t0 = 0.f, t1 = 0.f, t2 = 0.f, t3 = 0.f;
#pragma unroll
      for (int nt = 0; nt < 4; ++nt) {
        f32x4 cacc = {0.f, 0.f, 0.f, 0.f};
        cacc = __builtin_amdgcn_mfma_f32_16x16x32_bf16(a0, bfr[nt][0], cacc, 0, 0, 0);
        cacc = __builtin_amdgcn_mfma_f32_16x16x32_bf16(a1, bfr[nt][1], cacc, 0, 0, 0);
        t0 += fmaxf(fmaf(cacc[0], scl[nt], shf[nt]), 0.f) * wo[nt];
        t1 += fmaxf(fmaf(cacc[1], scl[nt], shf[nt]), 0.f) * wo[nt];
        t2 += fmaxf(fmaf(cacc[2], scl[nt], shf[nt]), 0.f) * wo[nt];
        t3 += fmaxf(fmaf(cacc[3], scl[nt], shf[nt]), 0.f) * wo[nt];
      }
      const int ebase = chunk * 64 + mt * 16 + 4 * l4;
#pragma unroll
      for (int j = 0; j < 4; ++j) {
        float r = (j == 0) ? t0 : (j == 1) ? t1 : (j == 2) ? t2 : t3;
        r += __shfl_xor(r, 1, 64);
        r += __shfl_xor(r, 2, 64);
        r += __shfl_xor(r, 4, 64);
        r += __shfl_xor(r, 8, 64);
        if (l15 == 0) out[ebase + j] = r + bo;
      }
    }
  }
}

extern "C" void kernel_launch(void* const* d_in, const int* in_sizes, int n_in,
                              void* d_out, int out_size, void* d_ws, size_t ws_size,
                              hipStream_t stream) {
  const float* x     = (const float*)d_in[0];
  const void*  edges = d_in[1];
  const float* W_in  = (const float*)d_in[2];
  const float* b_in  = (const float*)d_in[3];
  const float* W_h   = (const float*)d_in[4];
  const float* gamma = (const float*)d_in[6];
  const float* beta  = (const float*)d_in[7];
  const float* W_out = (const float*)d_in[8];
  const float* b_out = (const float*)d_in[9];
  float* out = (float*)d_out;

  char* base = (char*)d_ws;
  __hip_bfloat16* A = (__hip_bfloat16*)base;
  float* stats = (float*)(base + (size_t)N_NODES * 128 * sizeof(__hip_bfloat16));
  float* ss    = stats + 128;
  int*   flag  = (int*)(ss + 128);

  k_probe<<<1, 64, 0, stream>>>((const unsigned*)edges, flag);
  k1_mfma<<<782, 256, 0, stream>>>(x, W_in, b_in, A, stats);
  k2_stats<<<1024, 256, 0, stream>>>(A, edges, flag, W_h, stats);
  k3_finalize<<<1, 64, 0, stream>>>(stats, gamma, beta, ss);
  k4_out<<<1024, 256, 0, stream>>>(A, edges, flag, W_h, ss, W_out, b_out, out);
}

// Round 4
// 219.950 us; speedup vs baseline: 3.2920x; 1.1067x over previous
//
#include <hip/hip_runtime.h>
#include <hip/hip_bf16.h>
#include <hip/hip_fp16.h>

#define N_NODES 100000
#define N_EDGES 1000000
#define BN_EPS 1e-5f
#define N_CHUNKS (N_EDGES / 64)

typedef __attribute__((ext_vector_type(8))) short bf16x8;
typedef __attribute__((ext_vector_type(4))) float f32x4;

// ---------------- ws layout ----------------
// A     : [N_NODES][128] bf16 (25.6 MB)
// stats : 128 f32 (S1, S2) at offset 25.6MB;  ss : 128 f32;  flag : int
// g     : [N_CHUNKS][4mt][4nt][64 lane][4] fp16 (128 MB) at offset 25.6MB+4KB (if ws_size allows)

__device__ __forceinline__ unsigned pk2(float a, float b) {  // 2x bf16 RNE pack
  unsigned ua = __builtin_bit_cast(unsigned, a);
  unsigned ub = __builtin_bit_cast(unsigned, b);
  ua += 0x7fffu + ((ua >> 16) & 1u);
  ub += 0x7fffu + ((ub >> 16) & 1u);
  return (ua >> 16) | (ub & 0xffff0000u);
}

__device__ __forceinline__ bf16x8 pack8(float4 v0, float4 v1) {
  uint4 u = make_uint4(pk2(v0.x, v0.y), pk2(v0.z, v0.w), pk2(v1.x, v1.y), pk2(v1.z, v1.w));
  return __builtin_bit_cast(bf16x8, u);
}

// A-fragment from two 16B bf16 slices: relu(a + d), packed bf16.
__device__ __forceinline__ bf16x8 frag_relu_add(uint4 a, uint4 d) {
  uint4 r;
  const unsigned* aw = (const unsigned*)&a;
  const unsigned* dw = (const unsigned*)&d;
  unsigned* rw = (unsigned*)&r;
#pragma unroll
  for (int q = 0; q < 4; ++q) {
    const float alo = __builtin_bit_cast(float, aw[q] << 16);
    const float ahi = __builtin_bit_cast(float, aw[q] & 0xffff0000u);
    const float dlo = __builtin_bit_cast(float, dw[q] << 16);
    const float dhi = __builtin_bit_cast(float, dw[q] & 0xffff0000u);
    rw[q] = pk2(fmaxf(alo + dlo, 0.f), fmaxf(ahi + dhi, 0.f));
  }
  return __builtin_bit_cast(bf16x8, r);
}

// W_h B-fragments loaded directly from global in fragment layout (no LDS).
__device__ __forceinline__ void load_bfr(const float* __restrict__ W_h, int l15, int l4,
                                         bf16x8 bfr[4][2]) {
#pragma unroll
  for (int nt = 0; nt < 4; ++nt)
#pragma unroll
    for (int kk = 0; kk < 2; ++kk) {
      const float* wp = W_h + (16 * nt + l15) * 64 + (kk * 4 + l4) * 8;
      bfr[nt][kk] = pack8(*(const float4*)wp, *(const float4*)(wp + 4));
    }
}

__global__ __launch_bounds__(64) void k_probe(const unsigned* __restrict__ eu,
                                              int* __restrict__ flag) {
  if (threadIdx.x == 0) {
    unsigned acc = 0;
#pragma unroll
    for (int i = 1; i < 64; i += 2) acc |= eu[i];
    *flag = (acc == 0) ? 1 : 0;
  }
}

// K1: A = x @ Wcat^T via swapped-operand MFMA (C^T = Wcat . x^T), no LDS.
__global__ __launch_bounds__(256) void k1_mfma(
    const float* __restrict__ x, const float* __restrict__ W_in,
    const float* __restrict__ b_in, __hip_bfloat16* __restrict__ A,
    float* __restrict__ stats) {
  const int t = threadIdx.x;
  if (blockIdx.x == 0 && t < 128) stats[t] = 0.f;
  const int lane = t & 63;
  const int w = t >> 6;
  const int l15 = lane & 15, l4 = lane >> 4;
  const int nb = blockIdx.x * 128 + (w >> 1) * 64;
  const int cb = (w & 1) * 64;

  bf16x8 wfrag[4][4];
#pragma unroll
  for (int ct = 0; ct < 4; ++ct) {
#pragma unroll
    for (int kk = 0; kk < 4; ++kk) {
      const float* wp = W_in + (16 * ct + l15) * 256 + (cb ? 128 : 0) + 32 * kk + 8 * l4;
      wfrag[ct][kk] = pack8(*(const float4*)wp, *(const float4*)(wp + 4));
    }
  }
  f32x4 acc[4][4];
#pragma unroll
  for (int nt = 0; nt < 4; ++nt)
#pragma unroll
    for (int ct = 0; ct < 4; ++ct)
      acc[nt][ct] = (f32x4){0.f, 0.f, 0.f, 0.f};

#pragma unroll
  for (int nt = 0; nt < 4; ++nt) {
    int node = nb + 16 * nt + l15;
    node = node < N_NODES ? node : N_NODES - 1;
    const float* xr = x + (size_t)node * 128 + 8 * l4;
#pragma unroll
    for (int kk = 0; kk < 4; ++kk) {
      const bf16x8 xf = pack8(*(const float4*)(xr + 32 * kk), *(const float4*)(xr + 32 * kk + 4));
#pragma unroll
      for (int ct = 0; ct < 4; ++ct)
        acc[nt][ct] = __builtin_amdgcn_mfma_f32_16x16x32_bf16(wfrag[ct][kk], xf, acc[nt][ct], 0, 0, 0);
    }
  }

  float4 bv[4];
#pragma unroll
  for (int ct = 0; ct < 4; ++ct)
    bv[ct] = cb ? make_float4(0.f, 0.f, 0.f, 0.f) : *(const float4*)(b_in + 16 * ct + 4 * l4);
#pragma unroll
  for (int nt = 0; nt < 4; ++nt) {
    const int node = nb + 16 * nt + l15;
    if (node < N_NODES) {
      __hip_bfloat16* ap = A + (size_t)node * 128 + cb + 4 * l4;
#pragma unroll
      for (int ct = 0; ct < 4; ++ct) {
        uint2 u;
        u.x = pk2(acc[nt][ct][0] + bv[ct].x, acc[nt][ct][1] + bv[ct].y);
        u.y = pk2(acc[nt][ct][2] + bv[ct].z, acc[nt][ct][3] + bv[ct].w);
        *(uint2*)(ap + 16 * ct) = u;
      }
    }
  }
}

// K2: BN stats over g = h1 @ W_h^T. LDS-free: A-frags gathered directly in
// fragment layout (lane reads 16B of edge (16mt+l15)'s A row at chunk kk*4+l4),
// relu-add-pack in register. Optionally spills g (fp16, tile-native) for k4.
template<bool STORE_G>
__global__ __launch_bounds__(256) void k2_stats(
    const __hip_bfloat16* __restrict__ A, const void* __restrict__ edges,
    const int* __restrict__ flag, const float* __restrict__ W_h,
    float* __restrict__ stats, __half* __restrict__ g) {
  const int lane = threadIdx.x & 63;
  const int l15 = lane & 15, l4 = lane >> 4;
  bf16x8 bfr[4][2];
  load_bfr(W_h, l15, l4, bfr);

  const int is64 = *flag;
  const long long* e64 = (const long long*)edges;
  const int* e32 = (const int*)edges;
  float vs[4] = {0.f, 0.f, 0.f, 0.f};
  float vq[4] = {0.f, 0.f, 0.f, 0.f};
  const int gwave = blockIdx.x * 4 + (threadIdx.x >> 6);
  const int nwaves = gridDim.x * 4;
  for (int chunk = gwave; chunk < N_CHUNKS; chunk += nwaves) {
    const int base = chunk * 64;
#pragma unroll
    for (int mt = 0; mt < 4; ++mt) {
      const int eidx = base + mt * 16 + l15;
      int s, d;
      if (is64) { s = (int)e64[eidx]; d = (int)e64[N_EDGES + eidx]; }
      else      { s = e32[eidx];      d = e32[N_EDGES + eidx]; }
      const uint4* As = (const uint4*)(A + (size_t)s * 128);
      const uint4* Ad = (const uint4*)(A + (size_t)d * 128 + 64);
      const uint4 as0 = As[l4], as1 = As[4 + l4];
      const uint4 ad0 = Ad[l4], ad1 = Ad[4 + l4];
      const bf16x8 a0 = frag_relu_add(as0, ad0);
      const bf16x8 a1 = frag_relu_add(as1, ad1);
#pragma unroll
      for (int nt = 0; nt < 4; ++nt) {
        f32x4 c = {0.f, 0.f, 0.f, 0.f};
        c = __builtin_amdgcn_mfma_f32_16x16x32_bf16(a0, bfr[nt][0], c, 0, 0, 0);
        c = __builtin_amdgcn_mfma_f32_16x16x32_bf16(a1, bfr[nt][1], c, 0, 0, 0);
        if (STORE_G) {
          const __half2 h0 = __floats2half2_rn(c[0], c[1]);
          const __half2 h1 = __floats2half2_rn(c[2], c[3]);
          uint2 u;
          u.x = __builtin_bit_cast(unsigned, h0);
          u.y = __builtin_bit_cast(unsigned, h1);
          *(uint2*)(g + ((((size_t)chunk * 4 + mt) * 4 + nt) * 64 + lane) * 4) = u;
        }
#pragma unroll
        for (int j = 0; j < 4; ++j) {
          vs[nt] += c[j];
          vq[nt] += c[j] * c[j];
        }
      }
    }
  }
#pragma unroll
  for (int nt = 0; nt < 4; ++nt) {
    float s1 = vs[nt], s2 = vq[nt];
    s1 += __shfl_xor(s1, 16, 64); s1 += __shfl_xor(s1, 32, 64);
    s2 += __shfl_xor(s2, 16, 64); s2 += __shfl_xor(s2, 32, 64);
    if (lane < 16) {
      atomicAdd(&stats[lane + 16 * nt], s1);
      atomicAdd(&stats[64 + lane + 16 * nt], s2);
    }
  }
}

// K3: fold BN into per-channel scale/shift (b_h cancels exactly).
__global__ __launch_bounds__(64) void k3_finalize(
    const float* __restrict__ stats, const float* __restrict__ gamma,
    const float* __restrict__ beta, float* __restrict__ ss) {
  const int c = threadIdx.x;
  if (c < 64) {
    const float inv_e = 1.f / (float)N_EDGES;
    const float mg = stats[c] * inv_e;
    const float var = stats[64 + c] * inv_e - mg * mg;
    const float scale = gamma[c] * rsqrtf(var + BN_EPS);
    ss[c] = scale;
    ss[64 + c] = beta[c] - scale * mg;
  }
}

// K4a: streaming finish from spilled g (coalesced, memory-bound).
__global__ __launch_bounds__(256) void k4_stream(
    const __half* __restrict__ g, const float* __restrict__ ss,
    const float* __restrict__ W_out, const float* __restrict__ b_out,
    float* __restrict__ out) {
  const int lane = threadIdx.x & 63;
  const int l15 = lane & 15, l4 = lane >> 4;
  float scl[4], shf[4], wo[4];
#pragma unroll
  for (int nt = 0; nt < 4; ++nt) {
    scl[nt] = ss[l15 + 16 * nt];
    shf[nt] = ss[64 + l15 + 16 * nt];
    wo[nt] = W_out[l15 + 16 * nt];
  }
  const float bo = b_out[0];
  const int gwave = blockIdx.x * 4 + (threadIdx.x >> 6);
  const int nwaves = gridDim.x * 4;
  for (int chunk = gwave; chunk < N_CHUNKS; chunk += nwaves) {
#pragma unroll
    for (int mt = 0; mt < 4; ++mt) {
      float t0 = 0.f, t1 = 0.f, t2 = 0.f, t3 = 0.f;
#pragma unroll
      for (int nt = 0; nt < 4; ++nt) {
        const uint2 u = *(const uint2*)(g + ((((size_t)chunk * 4 + mt) * 4 + nt) * 64 + lane) * 4);
        const __half2 h0 = __builtin_bit_cast(__half2, u.x);
        const __half2 h1 = __builtin_bit_cast(__half2, u.y);
        t0 += fmaxf(fmaf(__low2float(h0),  scl[nt], shf[nt]), 0.f) * wo[nt];
        t1 += fmaxf(fmaf(__high2float(h0), scl[nt], shf[nt]), 0.f) * wo[nt];
        t2 += fmaxf(fmaf(__low2float(h1),  scl[nt], shf[nt]), 0.f) * wo[nt];
        t3 += fmaxf(fmaf(__high2float(h1), scl[nt], shf[nt]), 0.f) * wo[nt];
      }
      const int ebase = chunk * 64 + mt * 16 + 4 * l4;
#pragma unroll
      for (int j = 0; j < 4; ++j) {
        float r = (j == 0) ? t0 : (j == 1) ? t1 : (j == 2) ? t2 : t3;
        r += __shfl_xor(r, 1, 64);
        r += __shfl_xor(r, 2, 64);
        r += __shfl_xor(r, 4, 64);
        r += __shfl_xor(r, 8, 64);
        if (l15 == 0) out[ebase + j] = r + bo;
      }
    }
  }
}

// K4b: fallback — recompute g by gather+MFMA (LDS-free), then finish.
__global__ __launch_bounds__(256) void k4_gather(
    const __hip_bfloat16* __restrict__ A, const void* __restrict__ edges,
    const int* __restrict__ flag, const float* __restrict__ W_h,
    const float* __restrict__ ss, const float* __restrict__ W_out,
    const float* __restrict__ b_out, float* __restrict__ out) {
  const int lane = threadIdx.x & 63;
  const int l15 = lane & 15, l4 = lane >> 4;
  bf16x8 bfr[4][2];
  load_bfr(W_h, l15, l4, bfr);
  float scl[4], shf[4], wo[4];
#pragma unroll
  for (int nt = 0; nt < 4; ++nt) {
    scl[nt] = ss[l15 + 16 * nt];
    shf[nt] = ss[64 + l15 + 16 * nt];
    wo[nt] = W_out[l15 + 16 * nt];
  }
  const float bo = b_out[0];
  const int is64 = *flag;
  const long long* e64 = (const long long*)edges;
  const int* e32 = (const int*)edges;
  const int gwave = blockIdx.x * 4 + (threadIdx.x >> 6);
  const int nwaves = gridDim.x * 4;
  for (int chunk = gwave; chunk < N_CHUNKS; chunk += nwaves) {
    const int base = chunk * 64;
#pragma unroll
    for (int mt = 0; mt < 4; ++mt) {
      const int eidx = base + mt * 16 + l15;
      int s, d;
      if (is64) { s = (int)e64[eidx]; d = (int)e64[N_EDGES + eidx]; }
      else      { s = e32[eidx];      d = e32[N_EDGES + eidx]; }
      const uint4* As = (const uint4*)(A + (size_t)s * 128);
      const uint4* Ad = (const uint4*)(A + (size_t)d * 128 + 64);
      const bf16x8 a0 = frag_relu_add(As[l4], Ad[l4]);
      const bf16x8 a1 = frag_relu_add(As[4 + l4], Ad[4 + l4]);
      float t0 = 0.f, t1 = 0.f, t2 = 0.f, t3 = 0.f;
#pragma unroll
      for (int nt = 0; nt < 4; ++nt) {
        f32x4 c = {0.f, 0.f, 0.f, 0.f};
        c = __builtin_amdgcn_mfma_f32_16x16x32_bf16(a0, bfr[nt][0], c, 0, 0, 0);
        c = __builtin_amdgcn_mfma_f32_16x16x32_bf16(a1, bfr[nt][1], c, 0, 0, 0);
        t0 += fmaxf(fmaf(c[0], scl[nt], shf[nt]), 0.f) * wo[nt];
        t1 += fmaxf(fmaf(c[1], scl[nt], shf[nt]), 0.f) * wo[nt];
        t2 += fmaxf(fmaf(c[2], scl[nt], shf[nt]), 0.f) * wo[nt];
        t3 += fmaxf(fmaf(c[3], scl[nt], shf[nt]), 0.f) * wo[nt];
      }
      const int ebase = base + mt * 16 + 4 * l4;
#pragma unroll
      for (int j = 0; j < 4; ++j) {
        float r = (j == 0) ? t0 : (j == 1) ? t1 : (j == 2) ? t2 : t3;
        r += __shfl_xor(r, 1, 64);
        r += __shfl_xor(r, 2, 64);
        r += __shfl_xor(r, 4, 64);
        r += __shfl_xor(r, 8, 64);
        if (l15 == 0) out[ebase + j] = r + bo;
      }
    }
  }
}

extern "C" void kernel_launch(void* const* d_in, const int* in_sizes, int n_in,
                              void* d_out, int out_size, void* d_ws, size_t ws_size,
                              hipStream_t stream) {
  const float* x     = (const float*)d_in[0];
  const void*  edges = d_in[1];
  const float* W_in  = (const float*)d_in[2];
  const float* b_in  = (const float*)d_in[3];
  const float* W_h   = (const float*)d_in[4];
  const float* gamma = (const float*)d_in[6];
  const float* beta  = (const float*)d_in[7];
  const float* W_out = (const float*)d_in[8];
  const float* b_out = (const float*)d_in[9];
  float* out = (float*)d_out;

  char* base = (char*)d_ws;
  __hip_bfloat16* A = (__hip_bfloat16*)base;
  const size_t offStats = (size_t)N_NODES * 128 * sizeof(__hip_bfloat16);  // 25.6 MB
  float* stats = (float*)(base + offStats);
  float* ss    = stats + 128;
  int*   flag  = (int*)(ss + 128);
  const size_t offG = offStats + 4096;
  __half* g = (__half*)(base + offG);
  const bool use_g = ws_size >= offG + (size_t)N_EDGES * 64 * sizeof(__half);

  k_probe<<<1, 64, 0, stream>>>((const unsigned*)edges, flag);
  k1_mfma<<<782, 256, 0, stream>>>(x, W_in, b_in, A, stats);
  if (use_g) {
    k2_stats<true><<<1024, 256, 0, stream>>>(A, edges, flag, W_h, stats, g);
    k3_finalize<<<1, 64, 0, stream>>>(stats, gamma, beta, ss);
    k4_stream<<<1024, 256, 0, stream>>>(g, ss, W_out, b_out, out);
  } else {
    k2_stats<false><<<1024, 256, 0, stream>>>(A, edges, flag, W_h, stats, g);
    k3_finalize<<<1, 64, 0, stream>>>(stats, gamma, beta, ss);
    k4_gather<<<1024, 256, 0, stream>>>(A, edges, flag, W_h, ss, W_out, b_out, out);
  }
}